// Round 8
// baseline (113.079 us; speedup 1.0000x reference)
//
#include <hip/hip_runtime.h>

// SAHead: B=2, Cenc=326, C=320, dk=dv=64, L=64*64=4096.
// Cosine attention => scores in [-1,1] => exp() stable without max-subtraction
// => split-j partial softmax combines by plain addition.
//
// Pipeline (4 launches):
//   prep    : xpose x/xe -> Xt[b][l][384] bf16 (zero-pad) ; wconv W -> bf16[384]
//   proj    : MFMA GEMM, 4-wave K-split + LDS reduce; L2-normalize fused.
//   attn    : flash-style, split-j partial softmax, double-buffered LDS K/V
//             (ONE barrier per j-tile), S^T/O^T formulation; bf16 partials.
//   combine : sum bf16 split partials, divide by rowsum, transpose to [b][v][l]

#define L_DIM 4096
#define KPAD 384
#define NSPLIT 8

typedef __attribute__((ext_vector_type(8))) short bf16x8;  // 8 bf16 (4 VGPRs)
typedef __attribute__((ext_vector_type(4))) float f32x4;   // 4 fp32 acc

__device__ __forceinline__ unsigned short f2bf(float f) {
    // round-to-nearest-even fp32 -> bf16
    unsigned u = __float_as_uint(f);
    u += 0x7fffu + ((u >> 16) & 1u);
    return (unsigned short)(u >> 16);
}

__device__ __forceinline__ float bf2f(unsigned short h) {
    return __uint_as_float((unsigned)h << 16);
}

// ---------------------------------------------------------------------------
// Kernel 1: prep = xpose (z in [0,4)) + wconv (z == 4).
// ---------------------------------------------------------------------------
__global__ __launch_bounds__(256) void prep_kernel(
    const float* __restrict__ x, const float* __restrict__ xe,
    const float* __restrict__ Wq, const float* __restrict__ Wk,
    const float* __restrict__ Wv,
    unsigned short* __restrict__ xt_x, unsigned short* __restrict__ xt_xe,
    unsigned short* __restrict__ wbf)
{
    const int z = blockIdx.z;
    if (z == 4) {
        const int bid = blockIdx.y * 64 + blockIdx.x;
        const int idx = bid * 256 + threadIdx.x;
        if (idx >= 3 * 64 * KPAD) return;
        const int t = idx / (64 * KPAD);
        const int rem = idx - t * 64 * KPAD;
        const int d = rem / KPAD, c = rem - d * KPAD;
        const int Cin = (t == 2) ? 320 : 326;
        const float* W = (t == 0) ? Wq : (t == 1 ? Wk : Wv);
        wbf[idx] = (c < Cin) ? f2bf(W[(size_t)d * Cin + c]) : (unsigned short)0;
        return;
    }

    const int src_is_x = z >> 1, b = z & 1;
    const int c0 = blockIdx.y * 64;
    const int l0 = blockIdx.x * 64;
    const int Cin = src_is_x ? 320 : 326;
    const float* src = (src_is_x ? x : xe) + (size_t)b * Cin * L_DIM;
    unsigned short* dst = (src_is_x ? xt_x : xt_xe) + (size_t)b * L_DIM * KPAD;

    __shared__ float tile[64][65];
    const int tid = threadIdx.x;

    #pragma unroll
    for (int it = 0; it < 4; ++it) {
        const int idx = tid + it * 256;          // 1024 float4 loads
        const int cc = idx >> 4, lq = idx & 15;  // l = lq*4
        const int c = c0 + cc;
        float4 v = make_float4(0.f, 0.f, 0.f, 0.f);
        if (c < Cin) v = *(const float4*)(src + (size_t)c * L_DIM + l0 + lq * 4);
        tile[cc][lq * 4 + 0] = v.x;
        tile[cc][lq * 4 + 1] = v.y;
        tile[cc][lq * 4 + 2] = v.z;
        tile[cc][lq * 4 + 3] = v.w;
    }
    __syncthreads();
    #pragma unroll
    for (int it = 0; it < 4; ++it) {
        const int idx = tid + it * 256;
        const int ll = idx >> 4, cq = idx & 15;
        ushort4 o;
        o.x = f2bf(tile[cq * 4 + 0][ll]);
        o.y = f2bf(tile[cq * 4 + 1][ll]);
        o.z = f2bf(tile[cq * 4 + 2][ll]);
        o.w = f2bf(tile[cq * 4 + 3][ll]);
        *(ushort4*)(dst + (size_t)(l0 + ll) * KPAD + c0 + cq * 4) = o;
    }
}

// ---------------------------------------------------------------------------
// Kernel 2: MFMA projection, 4-wave K-split. grid (64 l-tiles, 6), 256 thr.
// Wave w handles ksteps [3w, 3w+3) of 12 (K=384, zero-padded so split exact).
// Waves 1..3 write partial acc to LDS; wave 0 adds + bias + (Q,K: L2-norm).
// MFMA 16x16x32 bf16 layouts:
//   A: lane holds A[m=lane&15][k=(lane>>4)*8+j]  (8 contiguous k)
//   B: lane holds B[k=(lane>>4)*8+j][n=lane&15]  (same register pattern as A)
//   D: lane holds D[row=(lane>>4)*4+r][col=lane&15]
// ---------------------------------------------------------------------------
__global__ __launch_bounds__(256) void proj_kernel(
    const unsigned short* __restrict__ xt_xe, const unsigned short* __restrict__ xt_x,
    const unsigned short* __restrict__ wbf,
    const float* __restrict__ bq, const float* __restrict__ bk,
    const float* __restrict__ bv,
    unsigned short* __restrict__ qn, unsigned short* __restrict__ kn,
    unsigned short* __restrict__ vbf)
{
    const int z = blockIdx.y;
    const int tensor = z >> 1, b = z & 1;
    const int l0 = blockIdx.x * 64;
    const int tid = threadIdx.x;
    const int w = tid >> 6, lane = tid & 63;
    const int q = lane >> 4, ln = lane & 15;

    const unsigned short* Xt = (tensor == 2 ? xt_x : xt_xe) + (size_t)b * L_DIM * KPAD;
    const unsigned short* W  = wbf + (size_t)tensor * 64 * KPAD;
    const float* bias = (tensor == 0) ? bq : (tensor == 1 ? bk : bv);

    __shared__ float red[3][64][68];   // waves 1..3 partial acc

    f32x4 acc[4][4];
    #pragma unroll
    for (int mf = 0; mf < 4; ++mf)
        #pragma unroll
        for (int nf = 0; nf < 4; ++nf) acc[mf][nf] = (f32x4){0.f, 0.f, 0.f, 0.f};

    const int kbase = w * 3 * 32;   // this wave's K range: 3 steps of 32

    bf16x8 af[4], bfr[4], afn[4], bfn[4];
    #pragma unroll
    for (int mf = 0; mf < 4; ++mf)
        af[mf] = *(const bf16x8*)(W + (size_t)(mf * 16 + ln) * KPAD + kbase + q * 8);
    #pragma unroll
    for (int nf = 0; nf < 4; ++nf)
        bfr[nf] = *(const bf16x8*)(Xt + (size_t)(l0 + nf * 16 + ln) * KPAD + kbase + q * 8);

    #pragma unroll
    for (int ks = 0; ks < 3; ++ks) {
        if (ks + 1 < 3) {
            const int c = kbase + (ks + 1) * 32 + q * 8;
            #pragma unroll
            for (int mf = 0; mf < 4; ++mf)
                afn[mf] = *(const bf16x8*)(W + (size_t)(mf * 16 + ln) * KPAD + c);
            #pragma unroll
            for (int nf = 0; nf < 4; ++nf)
                bfn[nf] = *(const bf16x8*)(Xt + (size_t)(l0 + nf * 16 + ln) * KPAD + c);
        }
        #pragma unroll
        for (int mf = 0; mf < 4; ++mf)
            #pragma unroll
            for (int nf = 0; nf < 4; ++nf)
                acc[mf][nf] = __builtin_amdgcn_mfma_f32_16x16x32_bf16(
                    af[mf], bfr[nf], acc[mf][nf], 0, 0, 0);
        #pragma unroll
        for (int mf = 0; mf < 4; ++mf) af[mf] = afn[mf];
        #pragma unroll
        for (int nf = 0; nf < 4; ++nf) bfr[nf] = bfn[nf];
    }

    // cross-wave reduce: waves 1..3 -> LDS, wave 0 accumulates
    if (w != 0) {
        #pragma unroll
        for (int mf = 0; mf < 4; ++mf)
            #pragma unroll
            for (int nf = 0; nf < 4; ++nf)
                *(f32x4*)&red[w - 1][lane][(mf * 4 + nf) * 4] = acc[mf][nf];
    }
    __syncthreads();
    if (w != 0) return;

    #pragma unroll
    for (int wi = 0; wi < 3; ++wi)
        #pragma unroll
        for (int mf = 0; mf < 4; ++mf)
            #pragma unroll
            for (int nf = 0; nf < 4; ++nf) {
                const f32x4 p = *(const f32x4*)&red[wi][lane][(mf * 4 + nf) * 4];
                acc[mf][nf] += p;
            }

    #pragma unroll
    for (int mf = 0; mf < 4; ++mf)
        #pragma unroll
        for (int r = 0; r < 4; ++r) {
            const float bb = bias[mf * 16 + q * 4 + r];
            #pragma unroll
            for (int nf = 0; nf < 4; ++nf) acc[mf][nf][r] += bb;
        }

    if (tensor < 2) {
        unsigned short* outp = (tensor ? kn : qn) + (size_t)b * L_DIM * 64;
        #pragma unroll
        for (int nf = 0; nf < 4; ++nf) {
            float s = 0.f;
            #pragma unroll
            for (int mf = 0; mf < 4; ++mf)
                #pragma unroll
                for (int r = 0; r < 4; ++r) s += acc[mf][nf][r] * acc[mf][nf][r];
            s += __shfl_xor(s, 16);
            s += __shfl_xor(s, 32);
            const float rn = 1.0f / fmaxf(sqrtf(s), 1e-6f);
            const size_t lrow = (size_t)(l0 + nf * 16 + ln) * 64;
            #pragma unroll
            for (int mf = 0; mf < 4; ++mf) {
                ushort4 o;
                o.x = f2bf(acc[mf][nf][0] * rn);
                o.y = f2bf(acc[mf][nf][1] * rn);
                o.z = f2bf(acc[mf][nf][2] * rn);
                o.w = f2bf(acc[mf][nf][3] * rn);
                *(ushort4*)(outp + lrow + mf * 16 + q * 4) = o;
            }
        }
    } else {
        unsigned short* outp = vbf + (size_t)b * 64 * L_DIM;
        #pragma unroll
        for (int mf = 0; mf < 4; ++mf)
            #pragma unroll
            for (int r = 0; r < 4; ++r) {
                const int v = mf * 16 + q * 4 + r;
                #pragma unroll
                for (int nf = 0; nf < 4; ++nf)
                    outp[(size_t)v * L_DIM + l0 + nf * 16 + ln] = f2bf(acc[mf][nf][r]);
            }
    }
}

// ---------------------------------------------------------------------------
// Kernel 3: attention, double-buffered LDS K/V (ONE barrier per j-tile),
// S^T/O^T formulation, bf16 partials.
// grid (32, NSPLIT, 2): x = 128-row i-tile, y = j-split, z = b. 4 waves;
// wave w owns i-strip [32w,32w+32) as two 16-row substrips (i = strip + ln).
// Iteration jt: read buf[jt&1], write prefetched tile into buf[(jt+1)&1],
// then a single __syncthreads. The vmcnt wait on the prefetch overlaps the
// whole compute phase; the write targets a buffer nobody reads this round.
// ---------------------------------------------------------------------------
__global__ __launch_bounds__(256) void attn_kernel(
    const unsigned short* __restrict__ qn, const unsigned short* __restrict__ kn,
    const unsigned short* __restrict__ vbf,
    unsigned short* __restrict__ opart, float* __restrict__ ssum)
{
    const int b = blockIdx.z, split = blockIdx.y;
    const int i0 = blockIdx.x * 128;
    const int tid = threadIdx.x;
    const int w = tid >> 6, lane = tid & 63, q = lane >> 4, ln = lane & 15;

    const unsigned short* Q = qn + (size_t)b * L_DIM * 64;   // [l][64]
    const unsigned short* K = kn + (size_t)b * L_DIM * 64;   // [l][64]
    const unsigned short* V = vbf + (size_t)b * 64 * L_DIM;  // [v][L]

    __shared__ unsigned short Kb[2][64][72];  // [buf][j][d], +8 pad
    __shared__ unsigned short Vb[2][64][72];  // [buf][v][j], +8 pad
    __shared__ unsigned short Pl[4][32][72];  // wave-private P strips [i][j]

    bf16x8 qa[2][2];
    #pragma unroll
    for (int s = 0; s < 2; ++s) {
        const unsigned short* qp = Q + (size_t)(i0 + w * 32 + s * 16 + ln) * 64 + q * 8;
        qa[s][0] = *(const bf16x8*)(qp);
        qa[s][1] = *(const bf16x8*)(qp + 32);
    }

    f32x4 acc[2][4];   // [s][vf]: O[i=ln][v=vf*16+q*4+r]
    #pragma unroll
    for (int s = 0; s < 2; ++s)
        #pragma unroll
        for (int vf = 0; vf < 4; ++vf) acc[s][vf] = (f32x4){0.f, 0.f, 0.f, 0.f};
    float rowsum[2] = {0.f, 0.f};
    const f32x4 zero = (f32x4){0.f, 0.f, 0.f, 0.f};

    const int jbase = split * (L_DIM / NSPLIT);
    const int JT = L_DIM / (NSPLIT * 64);   // 8 j-tiles per split

    // staging indices for this thread (2 b128 each for K and V)
    const int sr0 = tid >> 3, sc0 = (tid & 7) * 8;          // rows 0..31
    const int sr1 = (256 + tid) >> 3, sc1 = sc0;            // rows 32..63

    // prologue: stage tile 0 into buf 0
    {
        bf16x8 k0 = *(const bf16x8*)(K + (size_t)(jbase + sr0) * 64 + sc0);
        bf16x8 k1 = *(const bf16x8*)(K + (size_t)(jbase + sr1) * 64 + sc1);
        bf16x8 v0 = *(const bf16x8*)(V + (size_t)sr0 * L_DIM + jbase + sc0);
        bf16x8 v1 = *(const bf16x8*)(V + (size_t)sr1 * L_DIM + jbase + sc1);
        *(bf16x8*)&Kb[0][sr0][sc0] = k0;
        *(bf16x8*)&Kb[0][sr1][sc1] = k1;
        *(bf16x8*)&Vb[0][sr0][sc0] = v0;
        *(bf16x8*)&Vb[0][sr1][sc1] = v1;
    }
    __syncthreads();

    for (int jt = 0; jt < JT; ++jt) {
        const int cur = jt & 1, nxt = cur ^ 1;

        // issue next tile's global loads (held in regs across compute)
        bf16x8 k0, k1, v0, v1;
        const bool pf = (jt + 1 < JT);
        if (pf) {
            const int j0 = jbase + (jt + 1) * 64;
            k0 = *(const bf16x8*)(K + (size_t)(j0 + sr0) * 64 + sc0);
            k1 = *(const bf16x8*)(K + (size_t)(j0 + sr1) * 64 + sc1);
            v0 = *(const bf16x8*)(V + (size_t)sr0 * L_DIM + j0 + sc0);
            v1 = *(const bf16x8*)(V + (size_t)sr1 * L_DIM + j0 + sc1);
        }

        // K frags (A-operand): lane holds K[j=jf*16+ln][d=q*8..+7]
        bf16x8 kf[4][2];
        #pragma unroll
        for (int jf = 0; jf < 4; ++jf) {
            kf[jf][0] = *(const bf16x8*)&Kb[cur][jf * 16 + ln][q * 8];
            kf[jf][1] = *(const bf16x8*)&Kb[cur][jf * 16 + ln][q * 8 + 32];
        }

        // S^T = K.Q^T ; P = exp(S); b64 write j-contiguous into strip [i][j]
        #pragma unroll
        for (int s = 0; s < 2; ++s) {
            #pragma unroll
            for (int jf = 0; jf < 4; ++jf) {
                f32x4 st;
                st = __builtin_amdgcn_mfma_f32_16x16x32_bf16(kf[jf][0], qa[s][0], zero, 0, 0, 0);
                st = __builtin_amdgcn_mfma_f32_16x16x32_bf16(kf[jf][1], qa[s][1], st, 0, 0, 0);
                const float p0 = __expf(st[0]);
                const float p1 = __expf(st[1]);
                const float p2 = __expf(st[2]);
                const float p3 = __expf(st[3]);
                rowsum[s] += (p0 + p1) + (p2 + p3);
                ushort4 pk;
                pk.x = f2bf(p0); pk.y = f2bf(p1); pk.z = f2bf(p2); pk.w = f2bf(p3);
                *(ushort4*)&Pl[w][s * 16 + ln][jf * 16 + q * 4] = pk;
            }
        }

        // V frags (A-operand): lane holds V[v=vf*16+ln][j=q*8..+7]
        bf16x8 vfr[4][2];
        #pragma unroll
        for (int vf = 0; vf < 4; ++vf) {
            vfr[vf][0] = *(const bf16x8*)&Vb[cur][vf * 16 + ln][q * 8];
            vfr[vf][1] = *(const bf16x8*)&Vb[cur][vf * 16 + ln][q * 8 + 32];
        }

        // O^T += V.P^T  (P frag as B-operand: lane holds P[i=ln][j=q*8..+7])
        #pragma unroll
        for (int s = 0; s < 2; ++s) {
            const bf16x8 pb0 = *(const bf16x8*)&Pl[w][s * 16 + ln][q * 8];
            const bf16x8 pb1 = *(const bf16x8*)&Pl[w][s * 16 + ln][q * 8 + 32];
            #pragma unroll
            for (int vf = 0; vf < 4; ++vf) {
                acc[s][vf] = __builtin_amdgcn_mfma_f32_16x16x32_bf16(vfr[vf][0], pb0, acc[s][vf], 0, 0, 0);
                acc[s][vf] = __builtin_amdgcn_mfma_f32_16x16x32_bf16(vfr[vf][1], pb1, acc[s][vf], 0, 0, 0);
            }
        }

        // write prefetched tile into the idle buffer; single barrier
        if (pf) {
            *(bf16x8*)&Kb[nxt][sr0][sc0] = k0;
            *(bf16x8*)&Kb[nxt][sr1][sc1] = k1;
            *(bf16x8*)&Vb[nxt][sr0][sc0] = v0;
            *(bf16x8*)&Vb[nxt][sr1][sc1] = v1;
            __syncthreads();
        }
    }

    #pragma unroll
    for (int s = 0; s < 2; ++s) {
        rowsum[s] += __shfl_xor(rowsum[s], 16);
        rowsum[s] += __shfl_xor(rowsum[s], 32);
    }

    // O epilogue: bf16 ushort4 stores, i = strip + ln, v = vf*16+q*4..+3
    unsigned short* Op = opart + ((size_t)(b * NSPLIT + split) * L_DIM + i0 + w * 32) * 64;
    #pragma unroll
    for (int s = 0; s < 2; ++s)
        #pragma unroll
        for (int vf = 0; vf < 4; ++vf) {
            ushort4 o;
            o.x = f2bf(acc[s][vf][0]); o.y = f2bf(acc[s][vf][1]);
            o.z = f2bf(acc[s][vf][2]); o.w = f2bf(acc[s][vf][3]);
            *(ushort4*)&Op[(s * 16 + ln) * 64 + vf * 16 + q * 4] = o;
        }

    if (q == 0) {
        #pragma unroll
        for (int s = 0; s < 2; ++s)
            ssum[(size_t)(b * NSPLIT + split) * L_DIM + i0 + w * 32 + s * 16 + ln]
                = rowsum[s];
    }
}

// ---------------------------------------------------------------------------
// Kernel 4: sum the NSPLIT bf16 partials, divide by rowsum, transpose to
// out [b][v][l] fp32.
// ---------------------------------------------------------------------------
__global__ __launch_bounds__(256) void combine_kernel(
    const unsigned short* __restrict__ opart, const float* __restrict__ ssum,
    float* __restrict__ out)
{
    const int b = blockIdx.y;
    const int i0 = blockIdx.x * 64;
    const int tid = threadIdx.x;
    __shared__ float t[64][65];
    __shared__ float sinv[64];

    if (tid < 64) {
        float s = 0.f;
        for (int sp = 0; sp < NSPLIT; ++sp)
            s += ssum[(size_t)(b * NSPLIT + sp) * L_DIM + i0 + tid];
        sinv[tid] = 1.0f / s;
    }
    __syncthreads();
    for (int it = 0; it < 4; ++it) {
        const int idx = tid + it * 256;          // 1024: (i, vq)
        const int i = idx >> 4, vq = idx & 15;
        float a0 = 0.f, a1 = 0.f, a2 = 0.f, a3 = 0.f;
        for (int sp = 0; sp < NSPLIT; ++sp) {
            const ushort4 p = *(const ushort4*)&opart[
                (((size_t)(b * NSPLIT + sp) * L_DIM + i0 + i)) * 64 + vq * 4];
            a0 += bf2f(p.x); a1 += bf2f(p.y); a2 += bf2f(p.z); a3 += bf2f(p.w);
        }
        t[i][vq * 4 + 0] = a0;
        t[i][vq * 4 + 1] = a1;
        t[i][vq * 4 + 2] = a2;
        t[i][vq * 4 + 3] = a3;
    }
    __syncthreads();
    for (int idx = tid; idx < 4096; idx += 256) {
        const int v = idx >> 6, i = idx & 63;
        out[((size_t)(b * 64 + v)) * L_DIM + i0 + i] = t[i][v] * sinv[i];
    }
}

// ---------------------------------------------------------------------------
extern "C" void kernel_launch(void* const* d_in, const int* in_sizes, int n_in,
                              void* d_out, int out_size, void* d_ws, size_t ws_size,
                              hipStream_t stream)
{
    const float* x  = (const float*)d_in[0];
    const float* xe = (const float*)d_in[1];
    const float* Wq = (const float*)d_in[2];
    const float* bq = (const float*)d_in[3];
    const float* Wk = (const float*)d_in[4];
    const float* bk = (const float*)d_in[5];
    const float* Wv = (const float*)d_in[6];
    const float* bv = (const float*)d_in[7];
    float* out = (float*)d_out;

    char* ws = (char*)d_ws;
    unsigned short* qn   = (unsigned short*)(ws);                    // 0..1 MB
    unsigned short* kn   = (unsigned short*)(ws + (1u << 20));       // 1..2 MB
    unsigned short* vbf  = (unsigned short*)(ws + (2u << 20));       // 2..3 MB
    float*          ss   = (float*)(ws + (3u << 20));                // 3..3.25 MB
    unsigned short* wb   = (unsigned short*)(ws + (3u << 20) + (512u << 10));
    unsigned short* xtxe = (unsigned short*)(ws + (4u << 20));       // 4..10 MB
    unsigned short* xtx  = (unsigned short*)(ws + (10u << 20));      // 10..16 MB
    unsigned short* op   = (unsigned short*)(ws + (16u << 20));      // 16..24 MB

    prep_kernel<<<dim3(64, 6, 5), 256, 0, stream>>>(x, xe, Wq, Wk, Wv, xtx, xtxe, wb);
    proj_kernel<<<dim3(64, 6), 256, 0, stream>>>(xtxe, xtx, wb, bq, bk, bv, qn, kn, vbf);
    attn_kernel<<<dim3(32, NSPLIT, 2), 256, 0, stream>>>(qn, kn, vbf, op, ss);
    combine_kernel<<<dim3(64, 2), 256, 0, stream>>>(op, ss, out);
}